// Round 19
// baseline (852.350 us; speedup 1.0000x reference)
//
#include <hip/hip_runtime.h>
#include <hip/hip_bf16.h>

#define H 128
#define KMIX 20

using f32x4 = __attribute__((ext_vector_type(4))) float;
using bf8v  = __attribute__((ext_vector_type(8))) short;
using fv4   = __attribute__((ext_vector_type(4))) float;
using iv4   = __attribute__((ext_vector_type(4))) int;

// bf16 weight region offsets (in shorts); all matrices in FRAGMENT-SEQUENTIAL layout:
//   element ((nt*4+kk)*64 + lane)*8 + j  ==  W[k][n],  n = nt*16+(lane&15), k = kk*32+(lane>>4)*8+j
#define OFF_MW1T 0
#define OFF_MW2T 32768
#define OFF_AW1T 65536
#define OFF_AW2T 98304
#define OFF_WIHT 131072
#define OFF_WHHT 229376
#define OFF_TW1T 327680
#define OFF_TW2T 344064
#define OFF_TW3T 360448
#define OFF_PW1T 364544
#define OFF_PW2T 380928
#define OFF_PW3T 397312
#define OFF_WINT 401408
#define WTOTAL   434176

__device__ __forceinline__ short f2bf(float x){
  union { __hip_bfloat16 h; unsigned short u; } cv;
  cv.h = __float2bfloat16(x);
  return (short)cv.u;
}
__device__ __forceinline__ float bf2f(short b){
  union { unsigned u; float f; } v; v.u = ((unsigned)(unsigned short)b) << 16;
  return v.f;
}
__device__ __forceinline__ f32x4 mfma16(bf8v a, bf8v b, f32x4 c){
  return __builtin_amdgcn_mfma_f32_16x16x32_bf16(a, b, c, 0, 0, 0);
}
__device__ __forceinline__ bf8v pack_row(const float* __restrict__ p, int ko){
  float4 s0 = *(const float4*)(p + ko);
  float4 s1 = *(const float4*)(p + ko + 4);
  bf8v t;
  t[0]=f2bf(s0.x); t[1]=f2bf(s0.y); t[2]=f2bf(s0.z); t[3]=f2bf(s0.w);
  t[4]=f2bf(s1.x); t[5]=f2bf(s1.y); t[6]=f2bf(s1.z); t[7]=f2bf(s1.w);
  return t;
}
__device__ __forceinline__ bf8v pack_row_nt(const float* __restrict__ p, int ko){
  fv4 s0 = __builtin_nontemporal_load((const fv4*)(p + ko));
  fv4 s1 = __builtin_nontemporal_load((const fv4*)(p + ko + 4));
  bf8v t;
  t[0]=f2bf(s0[0]); t[1]=f2bf(s0[1]); t[2]=f2bf(s0[2]); t[3]=f2bf(s0[3]);
  t[4]=f2bf(s1[0]); t[5]=f2bf(s1[1]); t[6]=f2bf(s1[2]); t[7]=f2bf(s1[3]);
  return t;
}
// relu(bf16(s) - bf16(d) + bias[0..7]) -> bf16x8
__device__ __forceinline__ bf8v relu_db(bf8v s, bf8v d, const float* __restrict__ bias){
  float4 c0 = *(const float4*)(bias);
  float4 c1 = *(const float4*)(bias + 4);
  float cv[8] = {c0.x,c0.y,c0.z,c0.w,c1.x,c1.y,c1.z,c1.w};
  bf8v t;
#pragma unroll
  for (int j=0;j<8;j++){
    float v = bf2f(s[j]) - bf2f(d[j]) + cv[j];
    t[j] = f2bf(v > 0.f ? v : 0.f);
  }
  return t;
}

// ---------------- prep: convert all weights to bf16 in fragment-sequential layout
__global__ void prep_kernel(
    const float* __restrict__ msg_W1, const float* __restrict__ msg_W2,
    const float* __restrict__ att_W1, const float* __restrict__ att_W2,
    const float* __restrict__ gru_Wih, const float* __restrict__ gru_Whh,
    const float* __restrict__ theta_W1, const float* __restrict__ theta_W2, const float* __restrict__ theta_W3,
    const float* __restrict__ alpha_W1, const float* __restrict__ alpha_W2, const float* __restrict__ alpha_W3,
    const float* __restrict__ W_in, const float* __restrict__ msg_b1, const float* __restrict__ att_b1,
    short* __restrict__ wb, float* __restrict__ cbm, float* __restrict__ cba)
{
  const int j = blockIdx.x, tid = threadIdx.x;
  if (j < 12){
    const float* src; short* dst;
    switch(j){
      case 0:  src = msg_W1;             dst = wb + OFF_MW1T;        break;
      case 1:  src = msg_W1 + 256*128;   dst = wb + OFF_MW1T+16384;  break;
      case 2:  src = msg_W2;             dst = wb + OFF_MW2T;        break;
      case 3:  src = msg_W2 + 128*128;   dst = wb + OFF_MW2T+16384;  break;
      case 4:  src = att_W1;             dst = wb + OFF_AW1T;        break;
      case 5:  src = att_W1 + 256*128;   dst = wb + OFF_AW1T+16384;  break;
      case 6:  src = att_W2;             dst = wb + OFF_AW2T;        break;
      case 7:  src = att_W2 + 128*128;   dst = wb + OFF_AW2T+16384;  break;
      case 8:  src = theta_W1;           dst = wb + OFF_TW1T;        break;
      case 9:  src = theta_W2;           dst = wb + OFF_TW2T;        break;
      case 10: src = alpha_W1;           dst = wb + OFF_PW1T;        break;
      default: src = alpha_W2;           dst = wb + OFF_PW2T;        break;
    }
    for (int i = tid; i < 128*128; i += 256){
      int q = (i>>9)&31, kk = q&3, nt = q>>2;
      int lane = (i>>3)&63, jj = i&7;
      int n = nt*16 + (lane&15), k = kk*32 + (lane>>4)*8 + jj;
      dst[i] = f2bf(src[k*128 + n]);
    }
  } else if (j < 16){
    int q = j - 12;
    const float* src = (q < 2 ? gru_Wih : gru_Whh) + (q & 1) * 128*384;
    short* dst = wb + (q < 2 ? OFF_WIHT : OFF_WHHT) + (q & 1) * 49152;
    for (int i = tid; i < 3*128*128; i += 256){
      int g = i >> 14, rem = i & 16383;
      int qq = (rem>>9)&31, kk = qq&3, nt = qq>>2;
      int lane = (rem>>3)&63, jj = rem&7;
      int n = nt*16 + (lane&15), k = kk*32 + (lane>>4)*8 + jj;
      dst[i] = f2bf(src[k*384 + g*128 + n]);
    }
  } else if (j < 18){
    const float* src = (j == 16) ? theta_W3 : alpha_W3;
    short* dst = wb + ((j == 16) ? OFF_TW3T : OFF_PW3T);
    for (int i = tid; i < 32*128; i += 256){
      int q = i>>9, kk = q&3, nt = q>>2;
      int lane = (i>>3)&63, jj = i&7;
      int n = nt*16 + (lane&15), k = kk*32 + (lane>>4)*8 + jj;
      dst[i] = (n < KMIX) ? f2bf(src[k*KMIX + n]) : (short)0;
    }
  } else if (j == 18){
    for (int i = tid; i < 128*256; i += 256){
      int q = i>>9, kk = q&7, nt = q>>3;
      int lane = (i>>3)&63, jj = i&7;
      int n = nt*16 + (lane&15), k = kk*32 + (lane>>4)*8 + jj;
      wb[OFF_WINT + i] = f2bf(W_in[k*128 + n]);
    }
  } else {
    for (int i = tid; i < 2048; i += 256){
      int path = i >> 10, rem = i & 1023;
      int l = rem >> 9, rem2 = rem & 511;
      int combo = rem2 >> 7, c = rem2 & 127;
      int a = combo >> 1, b = combo & 1;
      const float* W  = path ? att_W1 : msg_W1;
      const float* bb = path ? att_b1 : msg_b1;
      float v = bb[l*128 + c] + W[(l*256 + 128 + a)*128 + c] + W[(l*256 + 192 + b)*128 + c];
      float* dst = path ? cba : cbm;
      dst[(l*4 + combo)*128 + c] = v;
    }
  }
}

// ---------------- sort-by-dst infrastructure (runs once) ----------------
__global__ void hist_kernel(const int* __restrict__ edges, int* __restrict__ counts, int M){
  int i = blockIdx.x*256 + threadIdx.x;
  if (i < M) atomicAdd(&counts[edges[2*i+1]], 1);
}

__global__ __launch_bounds__(1024)
void scanA_kernel(const int* __restrict__ counts, int* __restrict__ offs,
                  int* __restrict__ btot, int NK)
{
  __shared__ int buf[1024];
  const int tid = threadIdx.x;
  int i = blockIdx.x*1024 + tid;
  int v = (i < NK) ? counts[i] : 0;
  buf[tid] = v; __syncthreads();
#pragma unroll
  for (int off = 1; off < 1024; off <<= 1){
    int t = (tid >= off) ? buf[tid-off] : 0;
    __syncthreads();
    buf[tid] += t;
    __syncthreads();
  }
  if (i < NK) offs[i] = buf[tid] - v;
  if (tid == 1023) btot[blockIdx.x] = buf[1023];
}

__global__ __launch_bounds__(1024)
void scanB_kernel(int* __restrict__ btot, int NBLK)
{
  __shared__ int buf[1024];
  const int tid = threadIdx.x;
  int v = (tid < NBLK) ? btot[tid] : 0;
  buf[tid] = v; __syncthreads();
#pragma unroll
  for (int off = 1; off < 1024; off <<= 1){
    int t = (tid >= off) ? buf[tid-off] : 0;
    __syncthreads();
    buf[tid] += t;
    __syncthreads();
  }
  if (tid < NBLK) btot[tid] = buf[tid] - v;
}

__global__ __launch_bounds__(1024)
void scanC_kernel(int* __restrict__ offs, const int* __restrict__ btot,
                  int* __restrict__ cursor, int NK, int M)
{
  int i = blockIdx.x*1024 + threadIdx.x;
  if (i < NK){
    int o = offs[i] + btot[blockIdx.x];
    offs[i] = o;
    cursor[i] = o;
  }
  if (i == 0) offs[NK] = M;
}

// spk[p] = src | (combo<<20); pads [M, MPAD) with dst=NN sentinel
__global__ void scatter_kernel(const int* __restrict__ edges, const int* __restrict__ att_idx,
                               int* __restrict__ cursor, int* __restrict__ spk,
                               int* __restrict__ sdst, int M, int MPAD, int NN)
{
  int i = blockIdx.x*256 + threadIdx.x;
  if (i >= M){
    if (i < MPAD){ spk[i] = 0; sdst[i] = NN; }
    return;
  }
  int s = edges[2*i], d = edges[2*i+1];
  int p = atomicAdd(&cursor[d], 1);
  spk[p] = s | ((att_idx[s]*2 + att_idx[d]) << 20);
  sdst[p] = d;
}

// ---------------- node_feat = A_pad(4096x256) @ W_in + b_in   (f32 out)
__global__ __launch_bounds__(256)
void nodefeat_kernel(const float* __restrict__ A, const short* __restrict__ WinT,
                     const float* __restrict__ b_in, float* __restrict__ nf)
{
  const int tid = threadIdx.x, wave = tid>>6, lane = tid&63;
  const int col = lane&15, khi = lane>>4;
  const int rbase = blockIdx.x*64 + wave*16;
  const float* pa = A + (size_t)(rbase + col)*256;
  bf8v a[8];
#pragma unroll
  for (int kk=0;kk<8;kk++) a[kk] = pack_row_nt(pa, kk*32 + khi*8);
#pragma unroll
  for (int nt=0;nt<8;nt++){
    float bv = b_in[nt*16+col];
    f32x4 c = {bv,bv,bv,bv};
#pragma unroll
    for (int kk=0;kk<8;kk++){
      bf8v b = *(const bf8v*)(WinT + ((nt*8+kk)<<9) + (lane<<3));
      c = mfma16(a[kk], b, c);
    }
#pragma unroll
    for (int r=0;r<4;r++)
      nf[(size_t)(rbase + khi*4 + r)*H + nt*16+col] = c[r];
  }
}

// ---------------- fused gather + state write + layer-0 W1 GEMMs
__global__ __launch_bounds__(256)
void gnodemm_kernel(const float* __restrict__ nf, const int* __restrict__ nif,
                    const short* __restrict__ WT1, const short* __restrict__ WT2,
                    float* __restrict__ stOut, short* __restrict__ o1, short* __restrict__ o2,
                    int ostr, int NN)
{
  const int tid = threadIdx.x, wave = tid>>6, lane = tid&63;
  const int col = lane&15, khi = lane>>4;
  const int nbase = blockIdx.x*64 + wave*16;
  if (nbase >= NN) return;
  const int node = nbase + col;
  const int idx = (node < NN) ? nif[node] : 0;
  const float* px = nf + (size_t)(idx-1)*H;
  bf8v a[4];
  float* so = stOut + (size_t)node*H;
#pragma unroll
  for (int kk=0;kk<4;kk++){
    int ko = kk*32 + khi*8;
    float4 s0 = {0,0,0,0}, s1 = {0,0,0,0};
    if (idx > 0){ s0 = *(const float4*)(px + ko); s1 = *(const float4*)(px + ko + 4); }
    *(float4*)(so + ko)     = s0;
    *(float4*)(so + ko + 4) = s1;
    bf8v t;
    t[0]=f2bf(s0.x); t[1]=f2bf(s0.y); t[2]=f2bf(s0.z); t[3]=f2bf(s0.w);
    t[4]=f2bf(s1.x); t[5]=f2bf(s1.y); t[6]=f2bf(s1.z); t[7]=f2bf(s1.w);
    a[kk] = t;
  }
#pragma unroll
  for (int m=0;m<2;m++){
    const short* Wt = m ? WT2 : WT1;
    short* o = m ? o2 : o1;
#pragma unroll
    for (int nt=0;nt<8;nt++){
      f32x4 c = {0.f,0.f,0.f,0.f};
#pragma unroll
      for (int kk=0;kk<4;kk++){
        bf8v b = *(const bf8v*)(Wt + ((nt*4+kk)<<9) + (lane<<3));
        c = mfma16(a[kk], b, c);
      }
#pragma unroll
      for (int r=0;r<4;r++)
        o[(size_t)(nbase + khi*4 + r)*ostr + nt*16+col] = f2bf(c[r]);
    }
  }
}

// ---------------- edge kernel: 64 edges/wave (4 tiles), all gathers issued up front,
// compute/store/walk in two 2-tile passes through 8KB LDS; fused segmented-atomic agg
__global__ __launch_bounds__(256,2)
void edge_kernel(const short* __restrict__ UV,
                 const int* __restrict__ spk, const int* __restrict__ sdst,
                 const short* __restrict__ mW2T, const short* __restrict__ aW2T,
                 const float* __restrict__ cbm, const float* __restrict__ cba,
                 const float* __restrict__ mb2, const float* __restrict__ ab2,
                 float* __restrict__ agg, int MPAD)
{
  __shared__ __align__(16) char smem[4][8192];   // per wave: 2 tiles x [16 rows][256B]
  const int tid = threadIdx.x, wave = tid>>6, lane = tid&63;
  const int col = lane&15, khi = lane>>4;
  const int pbase = blockIdx.x*256 + wave*64;
  if (pbase >= MPAD) return;
  char* lds = smem[wave];

  // preload: src-row fragments for ALL 4 tiles (64 gathers in flight before compute)
  bf8v usr[4][4], vsr[4][4];
  int dA[4], cmA[4];
#pragma unroll
  for (int t=0;t<4;t++){
    const int p = pbase + t*16 + col;
    const int v = spk[p];
    dA[t] = sdst[p];
    cmA[t] = v >> 20;
    const short* us = UV + (size_t)(v & 0xFFFFF)*256;
#pragma unroll
    for (int kk=0;kk<4;kk++){
      int ko = kk*32 + khi*8;
      usr[t][kk] = *(const bf8v*)(us+ko);
      vsr[t][kk] = *(const bf8v*)(us+128+ko);
    }
  }
  // consume: dst loads inline (sorted -> L1 broadcast), build MFMA A-fragments
  bf8v am[4][4], aa[4][4];
#pragma unroll
  for (int t=0;t<4;t++){
    const short* ud = UV + (size_t)dA[t]*256;
    const float* cbmp = cbm + cmA[t]*H;
    const float* cbap = cba + cmA[t]*H;
#pragma unroll
    for (int kk=0;kk<4;kk++){
      int ko = kk*32 + khi*8;
      am[t][kk] = relu_db(usr[t][kk], *(const bf8v*)(ud+ko),     cbmp+ko);
      aa[t][kk] = relu_db(vsr[t][kk], *(const bf8v*)(ud+128+ko), cbap+ko);
    }
  }
#pragma unroll
  for (int half=0; half<2; ++half){
#pragma unroll
    for (int nt=0;nt<8;nt++){
      f32x4 c[2], c2[2];
#pragma unroll
      for (int t=0;t<2;t++){ c[t] = (f32x4){0.f,0.f,0.f,0.f}; c2[t] = (f32x4){0.f,0.f,0.f,0.f}; }
#pragma unroll
      for (int kk=0;kk<4;kk++){
        bf8v bm = *(const bf8v*)(mW2T + ((nt*4+kk)<<9) + (lane<<3));
        bf8v ba = *(const bf8v*)(aW2T + ((nt*4+kk)<<9) + (lane<<3));
#pragma unroll
        for (int t=0;t<2;t++){
          int tt = half*2 + t;
          c[t]  = mfma16(am[tt][kk], bm, c[t]);
          c2[t] = mfma16(aa[tt][kk], ba, c2[t]);
        }
      }
      int cc = nt*16 + col;
      float bm2 = mb2[cc], ba2 = ab2[cc];
#pragma unroll
      for (int t=0;t<2;t++){
#pragma unroll
        for (int r=0;r<4;r++){
          float m  = c[t][r] + bm2;
          float sg = 1.f/(1.f + __expf(-(c2[t][r] + ba2)));
          int row = khi*4 + r;
          int bo = (t<<12) + (row<<8) + cc*2;
          bo ^= ((khi&3)<<5) ^ ((r&1)<<4);       // bank swizzle (32 banks, 2-way max)
          *(short*)(lds + bo) = f2bf(m*sg);
        }
      }
    }
    // segmented reduction over this half's 32 dst-sorted rows
    {
      const int c0 = 2*lane;
      float acc0 = 0.f, acc1 = 0.f;
      const int base = pbase + half*32;
      int prev = sdst[base];
#pragma unroll
      for (int g=0; g<32; ++g){
        int dg = sdst[base + g];
        if (dg != prev){
          atomicAdd(&agg[(size_t)prev*H + c0], acc0);
          atomicAdd(&agg[(size_t)prev*H + c0 + 1], acc1);
          acc0 = 0.f; acc1 = 0.f; prev = dg;
        }
        int t = g >> 4, row = g & 15;
        int sw = (((row>>2)&3)<<5) ^ ((row&1)<<4);
        unsigned w = *(const unsigned*)(lds + (((t<<12) + (row<<8) + (lane<<2)) ^ sw));
        acc0 += bf2f((short)(w & 0xffff));
        acc1 += bf2f((short)(w >> 16));
      }
      atomicAdd(&agg[(size_t)prev*H + c0], acc0);
      atomicAdd(&agg[(size_t)prev*H + c0 + 1], acc1);
    }
  }
}

// ---------------- GRU + fused next-stage W1 GEMMs
__global__ __launch_bounds__(256)
void gru_uv_kernel(const float* __restrict__ xa, const float* __restrict__ hs,
                   const short* __restrict__ WihT, const short* __restrict__ WhhT,
                   const float* __restrict__ bih, const float* __restrict__ bhh,
                   float* __restrict__ stOut,
                   const short* __restrict__ W1a, const short* __restrict__ W1b,
                   short* __restrict__ o1, short* __restrict__ o2, int ostr,
                   int NN, int relu_out)
{
  __shared__ float smem[4][16][132];
  const int tid = threadIdx.x, wave = tid>>6, lane = tid&63;
  const int col = lane&15, khi = lane>>4;
  const int nbase = blockIdx.x*64 + wave*16;
  if (nbase >= NN) return;
  float (*tile)[132] = smem[wave];

  const float* px = xa + (size_t)(nbase + col)*H;
  const float* ph = hs + (size_t)(nbase + col)*H;
  bf8v ax[4], ah[4];
#pragma unroll
  for (int kk=0;kk<4;kk++){
    ax[kk] = pack_row(px, kk*32 + khi*8);
    ah[kk] = pack_row(ph, kk*32 + khi*8);
  }
#pragma unroll
  for (int nt=0;nt<8;nt++){
    f32x4 ar = {0.f,0.f,0.f,0.f}, az = {0.f,0.f,0.f,0.f};
    f32x4 ani = {0.f,0.f,0.f,0.f}, anh = {0.f,0.f,0.f,0.f};
    int nc = nt*16 + col;
#pragma unroll
    for (int kk=0;kk<4;kk++){
      int fo = ((nt*4+kk)<<9) + (lane<<3);
      ar  = mfma16(ax[kk], *(const bf8v*)(WihT + fo), ar);
      ar  = mfma16(ah[kk], *(const bf8v*)(WhhT + fo), ar);
      az  = mfma16(ax[kk], *(const bf8v*)(WihT + 16384 + fo), az);
      az  = mfma16(ah[kk], *(const bf8v*)(WhhT + 16384 + fo), az);
      ani = mfma16(ax[kk], *(const bf8v*)(WihT + 32768 + fo), ani);
      anh = mfma16(ah[kk], *(const bf8v*)(WhhT + 32768 + fo), anh);
    }
    float br  = bih[nc] + bhh[nc];
    float bz  = bih[128+nc] + bhh[128+nc];
    float bni = bih[256+nc], bnh = bhh[256+nc];
#pragma unroll
    for (int r=0;r<4;r++){
      int row = nbase + khi*4 + r;
      float rr = 1.f/(1.f + __expf(-(ar[r] + br)));
      float zz = 1.f/(1.f + __expf(-(az[r] + bz)));
      float nn = tanhf(ani[r] + bni + rr*(anh[r] + bnh));
      float h  = hs[(size_t)row*H + nc];
      float o  = (1.f - zz)*nn + zz*h;
      if (relu_out) o = o > 0.f ? o : 0.f;
      if (stOut) stOut[(size_t)row*H + nc] = o;
      tile[khi*4 + r][nc] = o;
    }
  }
  bf8v a[4];
#pragma unroll
  for (int kk=0;kk<4;kk++) a[kk] = pack_row(&tile[col][0], kk*32 + khi*8);
#pragma unroll
  for (int m=0;m<2;m++){
    const short* Wt = m ? W1b : W1a;
    short* o = m ? o2 : o1;
#pragma unroll
    for (int nt=0;nt<8;nt++){
      f32x4 c = {0.f,0.f,0.f,0.f};
#pragma unroll
      for (int kk=0;kk<4;kk++){
        bf8v b = *(const bf8v*)(Wt + ((nt*4+kk)<<9) + (lane<<3));
        c = mfma16(a[kk], b, c);
      }
#pragma unroll
      for (int r=0;r<4;r++)
        o[(size_t)(nbase + khi*4 + r)*ostr + nt*16+col] = f2bf(c[r]);
    }
  }
}

// ---------------- prediction head, BOTH paths in one grid (blockIdx.y)
__global__ __launch_bounds__(256,3)
void pred_kernel(const short* __restrict__ Pt, const short* __restrict__ Pa,
                 const int* __restrict__ nig,
                 const short* __restrict__ tW2T, const short* __restrict__ tW3T,
                 const float* __restrict__ tb1, const float* __restrict__ tb2, const float* __restrict__ tb3,
                 const short* __restrict__ pW2T, const short* __restrict__ pW3T,
                 const float* __restrict__ pb1, const float* __restrict__ pb2, const float* __restrict__ pb3,
                 float* __restrict__ outT, float* __restrict__ outA, int E)
{
  __shared__ __align__(16) unsigned char smem[4][8192];
  __shared__ __align__(16) float osmem[4][640];
  const int path = blockIdx.y;
  const short* P   = path ? Pa   : Pt;
  const short* W2T = path ? pW2T : tW2T;
  const short* W3T = path ? pW3T : tW3T;
  const float* b1  = path ? pb1  : tb1;
  const float* b2  = path ? pb2  : tb2;
  const float* b3  = path ? pb3  : tb3;
  float* out       = path ? outA : outT;
  const int tid = threadIdx.x, wave = tid>>6, lane = tid&63;
  const int col = lane&15, khi = lane>>4;
  const int ebase = blockIdx.x*128 + wave*32;
  if (ebase >= E) return;
  unsigned char* lds = &smem[wave][0];
  float* ost = osmem[wave];

  bf8v p0r[2][4], p1r[2][4];
#pragma unroll
  for (int t=0;t<2;t++){
    int e = ebase + t*16 + col;
    const short* q0 = P + (size_t)nig[2*e]*H;
    const short* q1 = P + (size_t)nig[2*e+1]*H;
#pragma unroll
    for (int kk=0;kk<4;kk++){
      int ko = kk*32 + khi*8;
      p0r[t][kk] = *(const bf8v*)(q0+ko);
      p1r[t][kk] = *(const bf8v*)(q1+ko);
    }
  }
  bf8v a1[2][4];
#pragma unroll
  for (int t=0;t<2;t++)
#pragma unroll
    for (int kk=0;kk<4;kk++){
      int ko = kk*32 + khi*8;
      a1[t][kk] = relu_db(p0r[t][kk], p1r[t][kk], b1+ko);
    }
#pragma unroll
  for (int nt=0;nt<8;nt++){
    float bv = b2[nt*16+col];
    f32x4 c[2];
#pragma unroll
    for (int t=0;t<2;t++) c[t] = (f32x4){bv,bv,bv,bv};
#pragma unroll
    for (int kk=0;kk<4;kk++){
      bf8v b = *(const bf8v*)(W2T + ((nt*4+kk)<<9) + (lane<<3));
#pragma unroll
      for (int t=0;t<2;t++) c[t] = mfma16(a1[t][kk], b, c[t]);
    }
#pragma unroll
    for (int t=0;t<2;t++)
#pragma unroll
      for (int r=0;r<4;r++){
        int row = t*16 + khi*4 + r, cc = nt*16 + col;
        float v = c[t][r]; v = v > 0.f ? v : 0.f;
        *(unsigned short*)(lds + ((row*256 + cc*2) ^ ((row&7)<<4))) = (unsigned short)f2bf(v);
      }
  }
#pragma unroll
  for (int t=0;t<2;t++){
    bf8v a3[4];
#pragma unroll
    for (int kk=0;kk<4;kk++){
      int row = t*16 + col;
      int cb = kk*64 + khi*16;
      a3[kk] = *(const bf8v*)(lds + ((row*256 + cb) ^ ((row&7)<<4)));
    }
    f32x4 c3[2];
#pragma unroll
    for (int nt=0;nt<2;nt++){
      f32x4 c = {0.f,0.f,0.f,0.f};
#pragma unroll
      for (int kk=0;kk<4;kk++){
        bf8v b = *(const bf8v*)(W3T + ((nt*4+kk)<<9) + (lane<<3));
        c = mfma16(a3[kk], b, c);
      }
      c3[nt] = c;
    }
    if (!path){
#pragma unroll
      for (int r=0;r<4;r++){
        int el = t*16 + khi*4 + r;
        ost[el*KMIX + col] = c3[0][r] + b3[col];
        if (col < 4) ost[el*KMIX + 16 + col] = c3[1][r] + b3[16+col];
      }
    } else {
#pragma unroll
      for (int r=0;r<4;r++){
        float v0 = c3[0][r] + b3[col];
        float v1 = (col < 4) ? (c3[1][r] + b3[16+col]) : -1e30f;
        float mx = fmaxf(v0, v1);
#pragma unroll
        for (int mk=1; mk<16; mk<<=1) mx = fmaxf(mx, __shfl_xor(mx, mk, 64));
        float se = __expf(v0-mx) + ((col < 4) ? __expf(v1-mx) : 0.f);
#pragma unroll
        for (int mk=1; mk<16; mk<<=1) se += __shfl_xor(se, mk, 64);
        float lse = mx + __logf(se);
        int el = t*16 + khi*4 + r;
        ost[el*KMIX + col] = v0 - lse;
        if (col < 4) ost[el*KMIX + 16 + col] = v1 - lse;
      }
    }
  }
  {
    fv4* dst = (fv4*)(out + (size_t)ebase*KMIX);
    const fv4* src = (const fv4*)ost;
#pragma unroll
    for (int i=0;i<2;i++)
      __builtin_nontemporal_store(src[lane + i*64], dst + lane + i*64);
    if (lane < 32)
      __builtin_nontemporal_store(src[lane + 128], dst + lane + 128);
  }
}

extern "C" void kernel_launch(void* const* d_in, const int* in_sizes, int n_in,
                              void* d_out, int out_size, void* d_ws, size_t ws_size,
                              hipStream_t stream)
{
  (void)n_in; (void)out_size; (void)ws_size;
  const float* A_pad   = (const float*)d_in[0];
  const int*   edges   = (const int*)d_in[1];
  const int*   nig     = (const int*)d_in[2];
  const int*   nif     = (const int*)d_in[3];
  const int*   atti    = (const int*)d_in[4];
  const float* W_in    = (const float*)d_in[5];
  const float* b_in    = (const float*)d_in[6];
  const float* msg_W1  = (const float*)d_in[7];
  const float* msg_b1  = (const float*)d_in[8];
  const float* msg_W2  = (const float*)d_in[9];
  const float* msg_b2  = (const float*)d_in[10];
  const float* att_W1  = (const float*)d_in[11];
  const float* att_b1  = (const float*)d_in[12];
  const float* att_W2  = (const float*)d_in[13];
  const float* att_b2  = (const float*)d_in[14];
  const float* gru_Wih = (const float*)d_in[15];
  const float* gru_bih = (const float*)d_in[16];
  const float* gru_Whh = (const float*)d_in[17];
  const float* gru_bhh = (const float*)d_in[18];
  const float* theta_W1 = (const float*)d_in[19];
  const float* theta_b1 = (const float*)d_in[20];
  const float* theta_W2 = (const float*)d_in[21];
  const float* theta_b2 = (const float*)d_in[22];
  const float* theta_W3 = (const float*)d_in[23];
  const float* theta_b3 = (const float*)d_in[24];
  const float* alpha_W1 = (const float*)d_in[25];
  const float* alpha_b1 = (const float*)d_in[26];
  const float* alpha_W2 = (const float*)d_in[27];
  const float* alpha_b2 = (const float*)d_in[28];
  const float* alpha_W3 = (const float*)d_in[29];
  const float* alpha_b3 = (const float*)d_in[30];

  const int M  = in_sizes[1] / 2;
  const int EP = in_sizes[2] / 2;
  const int NN = in_sizes[3];
  const int MPAD = (M + 255) & ~255;

  char* p = (char*)d_ws;
  float* node_feat = (float*)p; p += (size_t)4096*H*4;
  float* stateA    = (float*)p; p += (size_t)NN*H*4;
  float* stateB    = (float*)p; p += (size_t)NN*H*4;
  float* agg       = (float*)p; p += (size_t)(NN+1)*H*4;     // +1 scratch row for pad sentinel
  short* UV        = (short*)p; p += (size_t)(NN+1)*256*2;   // +1 zero row for pad sentinel
  short* U         = (short*)p; p += (size_t)NN*H*2;
  short* Vv        = (short*)p; p += (size_t)NN*H*2;
  short* wb        = (short*)p; p += (size_t)WTOTAL*2;
  float* cbm       = (float*)p; p += 2*4*H*4;
  float* cba       = (float*)p; p += 2*4*H*4;
  int*   counts    = (int*)p;  p += (size_t)(NN+4)*4;
  int*   offs      = (int*)p;  p += (size_t)(NN+4)*4;
  int*   cursor    = (int*)p;  p += (size_t)(NN+4)*4;
  int*   btot      = (int*)p;  p += (size_t)1024*4;
  int*   spk       = (int*)p;  p += (size_t)MPAD*4;
  int*   sdst      = (int*)p;  p += (size_t)MPAD*4;

  float* outT = (float*)d_out;
  float* outA = outT + (size_t)EP*KMIX;

  prep_kernel<<<20,256,0,stream>>>(msg_W1,msg_W2,att_W1,att_W2,gru_Wih,gru_Whh,
      theta_W1,theta_W2,theta_W3,alpha_W1,alpha_W2,alpha_W3,W_in,msg_b1,att_b1,
      wb,cbm,cba);
  nodefeat_kernel<<<64,256,0,stream>>>(A_pad, wb+OFF_WINT, b_in, node_feat);

  // one-time counting sort of edges by dst (hierarchical scan), padded to MPAD
  const int NBLK = (NN + 1023) / 1024;
  (void)hipMemsetAsync(counts, 0, (size_t)NN*4, stream);
  (void)hipMemsetAsync(UV + (size_t)NN*256, 0, 512, stream);   // zero sentinel UV row
  hist_kernel<<<(M+255)/256,256,0,stream>>>(edges, counts, M);
  scanA_kernel<<<NBLK,1024,0,stream>>>(counts, offs, btot, NN);
  scanB_kernel<<<1,1024,0,stream>>>(btot, NBLK);
  scanC_kernel<<<NBLK,1024,0,stream>>>(offs, btot, cursor, NN, M);
  scatter_kernel<<<(MPAD+255)/256,256,0,stream>>>(edges, atti, cursor, spk, sdst, M, MPAD, NN);

  // fused gather + stateA + layer-0 UV
  gnodemm_kernel<<<(NN+63)/64,256,0,stream>>>(node_feat, nif,
      wb+OFF_MW1T, wb+OFF_AW1T, stateA, UV, UV+128, 256, NN);

  // layer 0: edge (fused segmented-atomic agg) -> gru (fused UV for layer 1)
  (void)hipMemsetAsync(agg, 0, (size_t)NN*H*4, stream);
  edge_kernel<<<MPAD/256,256,0,stream>>>(UV, spk, sdst,
      wb+OFF_MW2T, wb+OFF_AW2T, cbm, cba, msg_b2, att_b2, agg, MPAD);
  gru_uv_kernel<<<(NN+63)/64,256,0,stream>>>(agg, stateA,
      wb+OFF_WIHT, wb+OFF_WHHT, gru_bih, gru_bhh, stateB,
      wb+OFF_MW1T+16384, wb+OFF_AW1T+16384, UV, UV+128, 256, NN, 1);

  // layer 1: edge -> gru (fused pred tables U,Vv; no f32 state out)
  (void)hipMemsetAsync(agg, 0, (size_t)NN*H*4, stream);
  edge_kernel<<<MPAD/256,256,0,stream>>>(UV, spk, sdst,
      wb+OFF_MW2T+16384, wb+OFF_AW2T+16384, cbm+4*H, cba+4*H,
      msg_b2+H, att_b2+H, agg, MPAD);
  gru_uv_kernel<<<(NN+63)/64,256,0,stream>>>(agg, stateB,
      wb+OFF_WIHT+49152, wb+OFF_WHHT+49152, gru_bih+384, gru_bhh+384, (float*)nullptr,
      wb+OFF_TW1T, wb+OFF_PW1T, U, Vv, 128, NN, 0);

  pred_kernel<<<dim3((EP+127)/128,2),256,0,stream>>>(U, Vv, nig,
      wb+OFF_TW2T, wb+OFF_TW3T, theta_b1, theta_b2, theta_b3,
      wb+OFF_PW2T, wb+OFF_PW3T, alpha_b1, alpha_b2, alpha_b3,
      outT, outA, EP);
}

// Round 20
// 547.434 us; speedup vs baseline: 1.5570x; 1.5570x over previous
//
#include <hip/hip_runtime.h>
#include <hip/hip_bf16.h>

#define H 128
#define KMIX 20

using f32x4 = __attribute__((ext_vector_type(4))) float;
using bf8v  = __attribute__((ext_vector_type(8))) short;
using fv4   = __attribute__((ext_vector_type(4))) float;
using iv4   = __attribute__((ext_vector_type(4))) int;

// bf16 weight region offsets (in shorts); all matrices in FRAGMENT-SEQUENTIAL layout:
//   element ((nt*4+kk)*64 + lane)*8 + j  ==  W[k][n],  n = nt*16+(lane&15), k = kk*32+(lane>>4)*8+j
#define OFF_MW1T 0
#define OFF_MW2T 32768
#define OFF_AW1T 65536
#define OFF_AW2T 98304
#define OFF_WIHT 131072
#define OFF_WHHT 229376
#define OFF_TW1T 327680
#define OFF_TW2T 344064
#define OFF_TW3T 360448
#define OFF_PW1T 364544
#define OFF_PW2T 380928
#define OFF_PW3T 397312
#define OFF_WINT 401408
#define WTOTAL   434176

__device__ __forceinline__ short f2bf(float x){
  union { __hip_bfloat16 h; unsigned short u; } cv;
  cv.h = __float2bfloat16(x);
  return (short)cv.u;
}
__device__ __forceinline__ float bf2f(short b){
  union { unsigned u; float f; } v; v.u = ((unsigned)(unsigned short)b) << 16;
  return v.f;
}
__device__ __forceinline__ f32x4 mfma16(bf8v a, bf8v b, f32x4 c){
  return __builtin_amdgcn_mfma_f32_16x16x32_bf16(a, b, c, 0, 0, 0);
}
__device__ __forceinline__ bf8v pack_row(const float* __restrict__ p, int ko){
  float4 s0 = *(const float4*)(p + ko);
  float4 s1 = *(const float4*)(p + ko + 4);
  bf8v t;
  t[0]=f2bf(s0.x); t[1]=f2bf(s0.y); t[2]=f2bf(s0.z); t[3]=f2bf(s0.w);
  t[4]=f2bf(s1.x); t[5]=f2bf(s1.y); t[6]=f2bf(s1.z); t[7]=f2bf(s1.w);
  return t;
}
__device__ __forceinline__ bf8v pack_row_nt(const float* __restrict__ p, int ko){
  fv4 s0 = __builtin_nontemporal_load((const fv4*)(p + ko));
  fv4 s1 = __builtin_nontemporal_load((const fv4*)(p + ko + 4));
  bf8v t;
  t[0]=f2bf(s0[0]); t[1]=f2bf(s0[1]); t[2]=f2bf(s0[2]); t[3]=f2bf(s0[3]);
  t[4]=f2bf(s1[0]); t[5]=f2bf(s1[1]); t[6]=f2bf(s1[2]); t[7]=f2bf(s1[3]);
  return t;
}
// relu(bf16(s) - bf16(d) + bias[0..7]) -> bf16x8
__device__ __forceinline__ bf8v relu_db(bf8v s, bf8v d, const float* __restrict__ bias){
  float4 c0 = *(const float4*)(bias);
  float4 c1 = *(const float4*)(bias + 4);
  float cv[8] = {c0.x,c0.y,c0.z,c0.w,c1.x,c1.y,c1.z,c1.w};
  bf8v t;
#pragma unroll
  for (int j=0;j<8;j++){
    float v = bf2f(s[j]) - bf2f(d[j]) + cv[j];
    t[j] = f2bf(v > 0.f ? v : 0.f);
  }
  return t;
}

// ---------------- prep: convert all weights to bf16 in fragment-sequential layout
__global__ void prep_kernel(
    const float* __restrict__ msg_W1, const float* __restrict__ msg_W2,
    const float* __restrict__ att_W1, const float* __restrict__ att_W2,
    const float* __restrict__ gru_Wih, const float* __restrict__ gru_Whh,
    const float* __restrict__ theta_W1, const float* __restrict__ theta_W2, const float* __restrict__ theta_W3,
    const float* __restrict__ alpha_W1, const float* __restrict__ alpha_W2, const float* __restrict__ alpha_W3,
    const float* __restrict__ W_in, const float* __restrict__ msg_b1, const float* __restrict__ att_b1,
    short* __restrict__ wb, float* __restrict__ cbm, float* __restrict__ cba)
{
  const int j = blockIdx.x, tid = threadIdx.x;
  if (j < 12){
    const float* src; short* dst;
    switch(j){
      case 0:  src = msg_W1;             dst = wb + OFF_MW1T;        break;
      case 1:  src = msg_W1 + 256*128;   dst = wb + OFF_MW1T+16384;  break;
      case 2:  src = msg_W2;             dst = wb + OFF_MW2T;        break;
      case 3:  src = msg_W2 + 128*128;   dst = wb + OFF_MW2T+16384;  break;
      case 4:  src = att_W1;             dst = wb + OFF_AW1T;        break;
      case 5:  src = att_W1 + 256*128;   dst = wb + OFF_AW1T+16384;  break;
      case 6:  src = att_W2;             dst = wb + OFF_AW2T;        break;
      case 7:  src = att_W2 + 128*128;   dst = wb + OFF_AW2T+16384;  break;
      case 8:  src = theta_W1;           dst = wb + OFF_TW1T;        break;
      case 9:  src = theta_W2;           dst = wb + OFF_TW2T;        break;
      case 10: src = alpha_W1;           dst = wb + OFF_PW1T;        break;
      default: src = alpha_W2;           dst = wb + OFF_PW2T;        break;
    }
    for (int i = tid; i < 128*128; i += 256){
      int q = (i>>9)&31, kk = q&3, nt = q>>2;
      int lane = (i>>3)&63, jj = i&7;
      int n = nt*16 + (lane&15), k = kk*32 + (lane>>4)*8 + jj;
      dst[i] = f2bf(src[k*128 + n]);
    }
  } else if (j < 16){
    int q = j - 12;
    const float* src = (q < 2 ? gru_Wih : gru_Whh) + (q & 1) * 128*384;
    short* dst = wb + (q < 2 ? OFF_WIHT : OFF_WHHT) + (q & 1) * 49152;
    for (int i = tid; i < 3*128*128; i += 256){
      int g = i >> 14, rem = i & 16383;
      int qq = (rem>>9)&31, kk = qq&3, nt = qq>>2;
      int lane = (rem>>3)&63, jj = rem&7;
      int n = nt*16 + (lane&15), k = kk*32 + (lane>>4)*8 + jj;
      dst[i] = f2bf(src[k*384 + g*128 + n]);
    }
  } else if (j < 18){
    const float* src = (j == 16) ? theta_W3 : alpha_W3;
    short* dst = wb + ((j == 16) ? OFF_TW3T : OFF_PW3T);
    for (int i = tid; i < 32*128; i += 256){
      int q = i>>9, kk = q&3, nt = q>>2;
      int lane = (i>>3)&63, jj = i&7;
      int n = nt*16 + (lane&15), k = kk*32 + (lane>>4)*8 + jj;
      dst[i] = (n < KMIX) ? f2bf(src[k*KMIX + n]) : (short)0;
    }
  } else if (j == 18){
    for (int i = tid; i < 128*256; i += 256){
      int q = i>>9, kk = q&7, nt = q>>3;
      int lane = (i>>3)&63, jj = i&7;
      int n = nt*16 + (lane&15), k = kk*32 + (lane>>4)*8 + jj;
      wb[OFF_WINT + i] = f2bf(W_in[k*128 + n]);
    }
  } else {
    for (int i = tid; i < 2048; i += 256){
      int path = i >> 10, rem = i & 1023;
      int l = rem >> 9, rem2 = rem & 511;
      int combo = rem2 >> 7, c = rem2 & 127;
      int a = combo >> 1, b = combo & 1;
      const float* W  = path ? att_W1 : msg_W1;
      const float* bb = path ? att_b1 : msg_b1;
      float v = bb[l*128 + c] + W[(l*256 + 128 + a)*128 + c] + W[(l*256 + 192 + b)*128 + c];
      float* dst = path ? cba : cbm;
      dst[(l*4 + combo)*128 + c] = v;
    }
  }
}

// ---------------- sort-by-dst infrastructure (runs once) ----------------
__global__ void hist_kernel(const int* __restrict__ edges, int* __restrict__ counts, int M){
  int i = blockIdx.x*256 + threadIdx.x;
  if (i < M) atomicAdd(&counts[edges[2*i+1]], 1);
}

__global__ __launch_bounds__(1024)
void scanA_kernel(const int* __restrict__ counts, int* __restrict__ offs,
                  int* __restrict__ btot, int NK)
{
  __shared__ int buf[1024];
  const int tid = threadIdx.x;
  int i = blockIdx.x*1024 + tid;
  int v = (i < NK) ? counts[i] : 0;
  buf[tid] = v; __syncthreads();
#pragma unroll
  for (int off = 1; off < 1024; off <<= 1){
    int t = (tid >= off) ? buf[tid-off] : 0;
    __syncthreads();
    buf[tid] += t;
    __syncthreads();
  }
  if (i < NK) offs[i] = buf[tid] - v;
  if (tid == 1023) btot[blockIdx.x] = buf[1023];
}

__global__ __launch_bounds__(1024)
void scanB_kernel(int* __restrict__ btot, int NBLK)
{
  __shared__ int buf[1024];
  const int tid = threadIdx.x;
  int v = (tid < NBLK) ? btot[tid] : 0;
  buf[tid] = v; __syncthreads();
#pragma unroll
  for (int off = 1; off < 1024; off <<= 1){
    int t = (tid >= off) ? buf[tid-off] : 0;
    __syncthreads();
    buf[tid] += t;
    __syncthreads();
  }
  if (tid < NBLK) btot[tid] = buf[tid] - v;
}

__global__ __launch_bounds__(1024)
void scanC_kernel(int* __restrict__ offs, const int* __restrict__ btot,
                  int* __restrict__ cursor, int NK, int M)
{
  int i = blockIdx.x*1024 + threadIdx.x;
  if (i < NK){
    int o = offs[i] + btot[blockIdx.x];
    offs[i] = o;
    cursor[i] = o;
  }
  if (i == 0) offs[NK] = M;
}

// spk[p] = src | (combo<<20); pads [M, M128) with dst=NN sentinel
__global__ void scatter_kernel(const int* __restrict__ edges, const int* __restrict__ att_idx,
                               int* __restrict__ cursor, int* __restrict__ spk,
                               int* __restrict__ sdst, int M, int M128, int NN)
{
  int i = blockIdx.x*256 + threadIdx.x;
  if (i >= M){
    if (i < M128){ spk[i] = 0; sdst[i] = NN; }
    return;
  }
  int s = edges[2*i], d = edges[2*i+1];
  int p = atomicAdd(&cursor[d], 1);
  spk[p] = s | ((att_idx[s]*2 + att_idx[d]) << 20);
  sdst[p] = d;
}

// ---------------- node_feat = A_pad(4096x256) @ W_in + b_in   (f32 out)
__global__ __launch_bounds__(256)
void nodefeat_kernel(const float* __restrict__ A, const short* __restrict__ WinT,
                     const float* __restrict__ b_in, float* __restrict__ nf)
{
  const int tid = threadIdx.x, wave = tid>>6, lane = tid&63;
  const int col = lane&15, khi = lane>>4;
  const int rbase = blockIdx.x*64 + wave*16;
  const float* pa = A + (size_t)(rbase + col)*256;
  bf8v a[8];
#pragma unroll
  for (int kk=0;kk<8;kk++) a[kk] = pack_row_nt(pa, kk*32 + khi*8);
#pragma unroll
  for (int nt=0;nt<8;nt++){
    float bv = b_in[nt*16+col];
    f32x4 c = {bv,bv,bv,bv};
#pragma unroll
    for (int kk=0;kk<8;kk++){
      bf8v b = *(const bf8v*)(WinT + ((nt*8+kk)<<9) + (lane<<3));
      c = mfma16(a[kk], b, c);
    }
#pragma unroll
    for (int r=0;r<4;r++)
      nf[(size_t)(rbase + khi*4 + r)*H + nt*16+col] = c[r];
  }
}

// ---------------- fused gather + state write + layer-0 W1 GEMMs
__global__ __launch_bounds__(256)
void gnodemm_kernel(const float* __restrict__ nf, const int* __restrict__ nif,
                    const short* __restrict__ WT1, const short* __restrict__ WT2,
                    float* __restrict__ stOut, short* __restrict__ o1, short* __restrict__ o2,
                    int ostr, int NN)
{
  const int tid = threadIdx.x, wave = tid>>6, lane = tid&63;
  const int col = lane&15, khi = lane>>4;
  const int nbase = blockIdx.x*64 + wave*16;
  if (nbase >= NN) return;
  const int node = nbase + col;
  const int idx = (node < NN) ? nif[node] : 0;
  const float* px = nf + (size_t)(idx-1)*H;
  bf8v a[4];
  float* so = stOut + (size_t)node*H;
#pragma unroll
  for (int kk=0;kk<4;kk++){
    int ko = kk*32 + khi*8;
    float4 s0 = {0,0,0,0}, s1 = {0,0,0,0};
    if (idx > 0){ s0 = *(const float4*)(px + ko); s1 = *(const float4*)(px + ko + 4); }
    *(float4*)(so + ko)     = s0;
    *(float4*)(so + ko + 4) = s1;
    bf8v t;
    t[0]=f2bf(s0.x); t[1]=f2bf(s0.y); t[2]=f2bf(s0.z); t[3]=f2bf(s0.w);
    t[4]=f2bf(s1.x); t[5]=f2bf(s1.y); t[6]=f2bf(s1.z); t[7]=f2bf(s1.w);
    a[kk] = t;
  }
#pragma unroll
  for (int m=0;m<2;m++){
    const short* Wt = m ? WT2 : WT1;
    short* o = m ? o2 : o1;
#pragma unroll
    for (int nt=0;nt<8;nt++){
      f32x4 c = {0.f,0.f,0.f,0.f};
#pragma unroll
      for (int kk=0;kk<4;kk++){
        bf8v b = *(const bf8v*)(Wt + ((nt*4+kk)<<9) + (lane<<3));
        c = mfma16(a[kk], b, c);
      }
#pragma unroll
      for (int r=0;r<4;r++)
        o[(size_t)(nbase + khi*4 + r)*ostr + nt*16+col] = f2bf(c[r]);
    }
  }
}

// ---------------- edge kernel: 32 edges/wave, preloaded src, contiguous weights,
// fused segmented reduction (padded arrays, branch-free paired-u32 walk)
__global__ __launch_bounds__(256,3)
void edge_kernel(const short* __restrict__ UV,
                 const int* __restrict__ spk, const int* __restrict__ sdst,
                 const short* __restrict__ mW2T, const short* __restrict__ aW2T,
                 const float* __restrict__ cbm, const float* __restrict__ cba,
                 const float* __restrict__ mb2, const float* __restrict__ ab2,
                 float* __restrict__ agg, int M128)
{
  __shared__ __align__(16) char smem[4][8192];   // per wave: 2 tiles x [16 rows][256B]
  const int tid = threadIdx.x, wave = tid>>6, lane = tid&63;
  const int col = lane&15, khi = lane>>4;
  const int pbase = blockIdx.x*128 + wave*32;
  if (pbase >= M128) return;
  char* lds = smem[wave];

  // preload: all src-row fragments into registers (16 loads issued back-to-back)
  bf8v usr[2][4], vsr[2][4];
  int dA[2], cmA[2];
#pragma unroll
  for (int t=0;t<2;t++){
    const int p = pbase + t*16 + col;
    const int v = spk[p];
    dA[t] = sdst[p];
    cmA[t] = v >> 20;
    const short* us = UV + (size_t)(v & 0xFFFFF)*256;
#pragma unroll
    for (int kk=0;kk<4;kk++){
      int ko = kk*32 + khi*8;
      usr[t][kk] = *(const bf8v*)(us+ko);
      vsr[t][kk] = *(const bf8v*)(us+128+ko);
    }
  }
  // consume: dst loads inline (sorted -> L1 broadcast), build MFMA A-fragments
  bf8v am[2][4], aa[2][4];
#pragma unroll
  for (int t=0;t<2;t++){
    const short* ud = UV + (size_t)dA[t]*256;
    const float* cbmp = cbm + cmA[t]*H;
    const float* cbap = cba + cmA[t]*H;
#pragma unroll
    for (int kk=0;kk<4;kk++){
      int ko = kk*32 + khi*8;
      am[t][kk] = relu_db(usr[t][kk], *(const bf8v*)(ud+ko),     cbmp+ko);
      aa[t][kk] = relu_db(vsr[t][kk], *(const bf8v*)(ud+128+ko), cbap+ko);
    }
  }
#pragma unroll
  for (int nt=0;nt<8;nt++){
    f32x4 c[2], c2[2];
#pragma unroll
    for (int t=0;t<2;t++){ c[t] = (f32x4){0.f,0.f,0.f,0.f}; c2[t] = (f32x4){0.f,0.f,0.f,0.f}; }
#pragma unroll
    for (int kk=0;kk<4;kk++){
      bf8v bm = *(const bf8v*)(mW2T + ((nt*4+kk)<<9) + (lane<<3));
      bf8v ba = *(const bf8v*)(aW2T + ((nt*4+kk)<<9) + (lane<<3));
#pragma unroll
      for (int t=0;t<2;t++){
        c[t]  = mfma16(am[t][kk], bm, c[t]);
        c2[t] = mfma16(aa[t][kk], ba, c2[t]);
      }
    }
    int cc = nt*16 + col;
    float bm2 = mb2[cc], ba2 = ab2[cc];
#pragma unroll
    for (int t=0;t<2;t++){
#pragma unroll
      for (int r=0;r<4;r++){
        float m  = c[t][r] + bm2;
        float sg = 1.f/(1.f + __expf(-(c2[t][r] + ba2)));
        int row = khi*4 + r;
        int bo = (t<<12) + (row<<8) + cc*2;
        bo ^= ((khi&3)<<5) ^ ((r&1)<<4);       // bank swizzle (32 banks, 2-way max)
        *(short*)(lds + bo) = f2bf(m*sg);
      }
    }
  }
  // segmented reduction: lane owns cols 2*lane, 2*lane+1 (one u32 read per row)
  {
    const int c0 = 2*lane;
    float acc0 = 0.f, acc1 = 0.f;
    int prev = sdst[pbase];
#pragma unroll
    for (int g=0; g<32; ++g){
      int dg = sdst[pbase + g];
      if (dg != prev){
        atomicAdd(&agg[(size_t)prev*H + c0], acc0);
        atomicAdd(&agg[(size_t)prev*H + c0 + 1], acc1);
        acc0 = 0.f; acc1 = 0.f; prev = dg;
      }
      int t = g >> 4, row = g & 15;
      int sw = (((row>>2)&3)<<5) ^ ((row&1)<<4);
      unsigned w = *(const unsigned*)(lds + (((t<<12) + (row<<8) + (lane<<2)) ^ sw));
      acc0 += bf2f((short)(w & 0xffff));
      acc1 += bf2f((short)(w >> 16));
    }
    atomicAdd(&agg[(size_t)prev*H + c0], acc0);
    atomicAdd(&agg[(size_t)prev*H + c0 + 1], acc1);
  }
}

// ---------------- GRU + fused next-stage W1 GEMMs
__global__ __launch_bounds__(256)
void gru_uv_kernel(const float* __restrict__ xa, const float* __restrict__ hs,
                   const short* __restrict__ WihT, const short* __restrict__ WhhT,
                   const float* __restrict__ bih, const float* __restrict__ bhh,
                   float* __restrict__ stOut,
                   const short* __restrict__ W1a, const short* __restrict__ W1b,
                   short* __restrict__ o1, short* __restrict__ o2, int ostr,
                   int NN, int relu_out)
{
  __shared__ float smem[4][16][132];
  const int tid = threadIdx.x, wave = tid>>6, lane = tid&63;
  const int col = lane&15, khi = lane>>4;
  const int nbase = blockIdx.x*64 + wave*16;
  if (nbase >= NN) return;
  float (*tile)[132] = smem[wave];

  const float* px = xa + (size_t)(nbase + col)*H;
  const float* ph = hs + (size_t)(nbase + col)*H;
  bf8v ax[4], ah[4];
#pragma unroll
  for (int kk=0;kk<4;kk++){
    ax[kk] = pack_row(px, kk*32 + khi*8);
    ah[kk] = pack_row(ph, kk*32 + khi*8);
  }
#pragma unroll
  for (int nt=0;nt<8;nt++){
    f32x4 ar = {0.f,0.f,0.f,0.f}, az = {0.f,0.f,0.f,0.f};
    f32x4 ani = {0.f,0.f,0.f,0.f}, anh = {0.f,0.f,0.f,0.f};
    int nc = nt*16 + col;
#pragma unroll
    for (int kk=0;kk<4;kk++){
      int fo = ((nt*4+kk)<<9) + (lane<<3);
      ar  = mfma16(ax[kk], *(const bf8v*)(WihT + fo), ar);
      ar  = mfma16(ah[kk], *(const bf8v*)(WhhT + fo), ar);
      az  = mfma16(ax[kk], *(const bf8v*)(WihT + 16384 + fo), az);
      az  = mfma16(ah[kk], *(const bf8v*)(WhhT + 16384 + fo), az);
      ani = mfma16(ax[kk], *(const bf8v*)(WihT + 32768 + fo), ani);
      anh = mfma16(ah[kk], *(const bf8v*)(WhhT + 32768 + fo), anh);
    }
    float br  = bih[nc] + bhh[nc];
    float bz  = bih[128+nc] + bhh[128+nc];
    float bni = bih[256+nc], bnh = bhh[256+nc];
#pragma unroll
    for (int r=0;r<4;r++){
      int row = nbase + khi*4 + r;
      float rr = 1.f/(1.f + __expf(-(ar[r] + br)));
      float zz = 1.f/(1.f + __expf(-(az[r] + bz)));
      float nn = tanhf(ani[r] + bni + rr*(anh[r] + bnh));
      float h  = hs[(size_t)row*H + nc];
      float o  = (1.f - zz)*nn + zz*h;
      if (relu_out) o = o > 0.f ? o : 0.f;
      if (stOut) stOut[(size_t)row*H + nc] = o;
      tile[khi*4 + r][nc] = o;
    }
  }
  bf8v a[4];
#pragma unroll
  for (int kk=0;kk<4;kk++) a[kk] = pack_row(&tile[col][0], kk*32 + khi*8);
#pragma unroll
  for (int m=0;m<2;m++){
    const short* Wt = m ? W1b : W1a;
    short* o = m ? o2 : o1;
#pragma unroll
    for (int nt=0;nt<8;nt++){
      f32x4 c = {0.f,0.f,0.f,0.f};
#pragma unroll
      for (int kk=0;kk<4;kk++){
        bf8v b = *(const bf8v*)(Wt + ((nt*4+kk)<<9) + (lane<<3));
        c = mfma16(a[kk], b, c);
      }
#pragma unroll
      for (int r=0;r<4;r++)
        o[(size_t)(nbase + khi*4 + r)*ostr + nt*16+col] = f2bf(c[r]);
    }
  }
}

// ---------------- prediction head, BOTH paths in one grid (blockIdx.y)
__global__ __launch_bounds__(256,3)
void pred_kernel(const short* __restrict__ Pt, const short* __restrict__ Pa,
                 const int* __restrict__ nig,
                 const short* __restrict__ tW2T, const short* __restrict__ tW3T,
                 const float* __restrict__ tb1, const float* __restrict__ tb2, const float* __restrict__ tb3,
                 const short* __restrict__ pW2T, const short* __restrict__ pW3T,
                 const float* __restrict__ pb1, const float* __restrict__ pb2, const float* __restrict__ pb3,
                 float* __restrict__ outT, float* __restrict__ outA, int E)
{
  __shared__ __align__(16) unsigned char smem[4][8192];
  __shared__ __align__(16) float osmem[4][640];
  const int path = blockIdx.y;
  const short* P   = path ? Pa   : Pt;
  const short* W2T = path ? pW2T : tW2T;
  const short* W3T = path ? pW3T : tW3T;
  const float* b1  = path ? pb1  : tb1;
  const float* b2  = path ? pb2  : tb2;
  const float* b3  = path ? pb3  : tb3;
  float* out       = path ? outA : outT;
  const int tid = threadIdx.x, wave = tid>>6, lane = tid&63;
  const int col = lane&15, khi = lane>>4;
  const int ebase = blockIdx.x*128 + wave*32;
  if (ebase >= E) return;
  unsigned char* lds = &smem[wave][0];
  float* ost = osmem[wave];

  bf8v p0r[2][4], p1r[2][4];
#pragma unroll
  for (int t=0;t<2;t++){
    int e = ebase + t*16 + col;
    const short* q0 = P + (size_t)nig[2*e]*H;
    const short* q1 = P + (size_t)nig[2*e+1]*H;
#pragma unroll
    for (int kk=0;kk<4;kk++){
      int ko = kk*32 + khi*8;
      p0r[t][kk] = *(const bf8v*)(q0+ko);
      p1r[t][kk] = *(const bf8v*)(q1+ko);
    }
  }
  bf8v a1[2][4];
#pragma unroll
  for (int t=0;t<2;t++)
#pragma unroll
    for (int kk=0;kk<4;kk++){
      int ko = kk*32 + khi*8;
      a1[t][kk] = relu_db(p0r[t][kk], p1r[t][kk], b1+ko);
    }
#pragma unroll
  for (int nt=0;nt<8;nt++){
    float bv = b2[nt*16+col];
    f32x4 c[2];
#pragma unroll
    for (int t=0;t<2;t++) c[t] = (f32x4){bv,bv,bv,bv};
#pragma unroll
    for (int kk=0;kk<4;kk++){
      bf8v b = *(const bf8v*)(W2T + ((nt*4+kk)<<9) + (lane<<3));
#pragma unroll
      for (int t=0;t<2;t++) c[t] = mfma16(a1[t][kk], b, c[t]);
    }
#pragma unroll
    for (int t=0;t<2;t++)
#pragma unroll
      for (int r=0;r<4;r++){
        int row = t*16 + khi*4 + r, cc = nt*16 + col;
        float v = c[t][r]; v = v > 0.f ? v : 0.f;
        *(unsigned short*)(lds + ((row*256 + cc*2) ^ ((row&7)<<4))) = (unsigned short)f2bf(v);
      }
  }
#pragma unroll
  for (int t=0;t<2;t++){
    bf8v a3[4];
#pragma unroll
    for (int kk=0;kk<4;kk++){
      int row = t*16 + col;
      int cb = kk*64 + khi*16;
      a3[kk] = *(const bf8v*)(lds + ((row*256 + cb) ^ ((row&7)<<4)));
    }
    f32x4 c3[2];
#pragma unroll
    for (int nt=0;nt<2;nt++){
      f32x4 c = {0.f,0.f,0.f,0.f};
#pragma unroll
      for (int kk=0;kk<4;kk++){
        bf8v b = *(const bf8v*)(W3T + ((nt*4+kk)<<9) + (lane<<3));
        c = mfma16(a3[kk], b, c);
      }
      c3[nt] = c;
    }
    if (!path){
#pragma unroll
      for (int r=0;r<4;r++){
        int el = t*16 + khi*4 + r;
        ost[el*KMIX + col] = c3[0][r] + b3[col];
        if (col < 4) ost[el*KMIX + 16 + col] = c3[1][r] + b3[16+col];
      }
    } else {
#pragma unroll
      for (int r=0;r<4;r++){
        float v0 = c3[0][r] + b3[col];
        float v1 = (col < 4) ? (c3[1][r] + b3[16+col]) : -1e30f;
        float mx = fmaxf(v0, v1);
#pragma unroll
        for (int mk=1; mk<16; mk<<=1) mx = fmaxf(mx, __shfl_xor(mx, mk, 64));
        float se = __expf(v0-mx) + ((col < 4) ? __expf(v1-mx) : 0.f);
#pragma unroll
        for (int mk=1; mk<16; mk<<=1) se += __shfl_xor(se, mk, 64);
        float lse = mx + __logf(se);
        int el = t*16 + khi*4 + r;
        ost[el*KMIX + col] = v0 - lse;
        if (col < 4) ost[el*KMIX + 16 + col] = v1 - lse;
      }
    }
  }
  {
    fv4* dst = (fv4*)(out + (size_t)ebase*KMIX);
    const fv4* src = (const fv4*)ost;
#pragma unroll
    for (int i=0;i<2;i++)
      __builtin_nontemporal_store(src[lane + i*64], dst + lane + i*64);
    if (lane < 32)
      __builtin_nontemporal_store(src[lane + 128], dst + lane + 128);
  }
}

extern "C" void kernel_launch(void* const* d_in, const int* in_sizes, int n_in,
                              void* d_out, int out_size, void* d_ws, size_t ws_size,
                              hipStream_t stream)
{
  (void)n_in; (void)out_size; (void)ws_size;
  const float* A_pad   = (const float*)d_in[0];
  const int*   edges   = (const int*)d_in[1];
  const int*   nig     = (const int*)d_in[2];
  const int*   nif     = (const int*)d_in[3];
  const int*   atti    = (const int*)d_in[4];
  const float* W_in    = (const float*)d_in[5];
  const float* b_in    = (const float*)d_in[6];
  const float* msg_W1  = (const float*)d_in[7];
  const float* msg_b1  = (const float*)d_in[8];
  const float* msg_W2  = (const float*)d_in[9];
  const float* msg_b2  = (const float*)d_in[10];
  const float* att_W1  = (const float*)d_in[11];
  const float* att_b1  = (const float*)d_in[12];
  const float* att_W2  = (const float*)d_in[13];
  const float* att_b2  = (const float*)d_in[14];
  const float* gru_Wih = (const float*)d_in[15];
  const float* gru_bih = (const float*)d_in[16];
  const float* gru_Whh = (const float*)d_in[17];
  const float* gru_bhh = (const float*)d_in[18];
  const float* theta_W1 = (const float*)d_in[19];
  const float* theta_b1 = (const float*)d_in[20];
  const float* theta_W2 = (const float*)d_in[21];
  const float* theta_b2 = (const float*)d_in[22];
  const float* theta_W3 = (const float*)d_in[23];
  const float* theta_b3 = (const float*)d_in[24];
  const float* alpha_W1 = (const float*)d_in[25];
  const float* alpha_b1 = (const float*)d_in[26];
  const float* alpha_W2 = (const float*)d_in[27];
  const float* alpha_b2 = (const float*)d_in[28];
  const float* alpha_W3 = (const float*)d_in[29];
  const float* alpha_b3 = (const float*)d_in[30];

  const int M  = in_sizes[1] / 2;
  const int EP = in_sizes[2] / 2;
  const int NN = in_sizes[3];
  const int M128 = (M + 127) & ~127;

  char* p = (char*)d_ws;
  float* node_feat = (float*)p; p += (size_t)4096*H*4;
  float* stateA    = (float*)p; p += (size_t)NN*H*4;
  float* stateB    = (float*)p; p += (size_t)NN*H*4;
  float* agg       = (float*)p; p += (size_t)(NN+1)*H*4;     // +1 scratch row for pad sentinel
  short* UV        = (short*)p; p += (size_t)(NN+1)*256*2;   // +1 zero row for pad sentinel
  short* U         = (short*)p; p += (size_t)NN*H*2;
  short* Vv        = (short*)p; p += (size_t)NN*H*2;
  short* wb        = (short*)p; p += (size_t)WTOTAL*2;
  float* cbm       = (float*)p; p += 2*4*H*4;
  float* cba       = (float*)p; p += 2*4*H*4;
  int*   counts    = (int*)p;  p += (size_t)(NN+4)*4;
  int*   offs      = (int*)p;  p += (size_t)(NN+4)*4;
  int*   cursor    = (int*)p;  p += (size_t)(NN+4)*4;
  int*   btot      = (int*)p;  p += (size_t)1024*4;
  int*   spk       = (int*)p;  p += (size_t)M128*4;
  int*   sdst      = (int*)p;  p += (size_t)M128*4;

  float* outT = (float*)d_out;
  float* outA = outT + (size_t)EP*KMIX;

  prep_kernel<<<20,256,0,stream>>>(msg_W1,msg_W2,att_W1,att_W2,gru_Wih,gru_Whh,
      theta_W1,theta_W2,theta_W3,alpha_W1,alpha_W2,alpha_W3,W_in,msg_b1,att_b1,
      wb,cbm,cba);
  nodefeat_kernel<<<64,256,0,stream>>>(A_pad, wb+OFF_WINT, b_in, node_feat);

  // one-time counting sort of edges by dst (hierarchical scan), padded to M128
  const int NBLK = (NN + 1023) / 1024;
  (void)hipMemsetAsync(counts, 0, (size_t)NN*4, stream);
  (void)hipMemsetAsync(UV + (size_t)NN*256, 0, 512, stream);   // zero sentinel UV row
  hist_kernel<<<(M+255)/256,256,0,stream>>>(edges, counts, M);
  scanA_kernel<<<NBLK,1024,0,stream>>>(counts, offs, btot, NN);
  scanB_kernel<<<1,1024,0,stream>>>(btot, NBLK);
  scanC_kernel<<<NBLK,1024,0,stream>>>(offs, btot, cursor, NN, M);
  scatter_kernel<<<(M128+255)/256,256,0,stream>>>(edges, atti, cursor, spk, sdst, M, M128, NN);

  // fused gather + stateA + layer-0 UV
  gnodemm_kernel<<<(NN+63)/64,256,0,stream>>>(node_feat, nif,
      wb+OFF_MW1T, wb+OFF_AW1T, stateA, UV, UV+128, 256, NN);

  // layer 0: edge (fused segmented-atomic agg) -> gru (fused UV for layer 1)
  (void)hipMemsetAsync(agg, 0, (size_t)NN*H*4, stream);
  edge_kernel<<<M128/128,256,0,stream>>>(UV, spk, sdst,
      wb+OFF_MW2T, wb+OFF_AW2T, cbm, cba, msg_b2, att_b2, agg, M128);
  gru_uv_kernel<<<(NN+63)/64,256,0,stream>>>(agg, stateA,
      wb+OFF_WIHT, wb+OFF_WHHT, gru_bih, gru_bhh, stateB,
      wb+OFF_MW1T+16384, wb+OFF_AW1T+16384, UV, UV+128, 256, NN, 1);

  // layer 1: edge -> gru (fused pred tables U,Vv; no f32 state out)
  (void)hipMemsetAsync(agg, 0, (size_t)NN*H*4, stream);
  edge_kernel<<<M128/128,256,0,stream>>>(UV, spk, sdst,
      wb+OFF_MW2T+16384, wb+OFF_AW2T+16384, cbm+4*H, cba+4*H,
      msg_b2+H, att_b2+H, agg, M128);
  gru_uv_kernel<<<(NN+63)/64,256,0,stream>>>(agg, stateB,
      wb+OFF_WIHT+49152, wb+OFF_WHHT+49152, gru_bih+384, gru_bhh+384, (float*)nullptr,
      wb+OFF_TW1T, wb+OFF_PW1T, U, Vv, 128, NN, 0);

  pred_kernel<<<dim3((EP+127)/128,2),256,0,stream>>>(U, Vv, nig,
      wb+OFF_TW2T, wb+OFF_TW3T, theta_b1, theta_b2, theta_b3,
      wb+OFF_PW2T, wb+OFF_PW3T, alpha_b1, alpha_b2, alpha_b3,
      outT, outA, EP);
}